// Round 4
// baseline (176.410 us; speedup 1.0000x reference)
//
#include <hip/hip_runtime.h>
#include <math.h>

#define NB 4
#define PP 256
#define CC 151
#define RR 51
#define CM 160                 // padded C (5 tiles of 32)
#define KS 64                  // split-K: 4 i's per block
#define NROW (NB*PP)           // 1024
#define RELTOT (NB*PP*PP*RR)   // 13,369,344 floats
#define ALIM (RELTOT - 8)
#define MLB 10240              // halves per l in m-layout: 8 oct * 160 c * 8 j

typedef _Float16 half8 __attribute__((ext_vector_type(8)));
typedef float floatx16 __attribute__((ext_vector_type(16)));

// ws layout (bytes): m1g, m2g, part
#define OFF_M1 ((size_t)0)
#define OFF_M2 (OFF_M1 + (size_t)CC*MLB*2)     // +3,092,480
#define OFF_PT (OFF_M2 + (size_t)CC*MLB*2)     // part: 64*1024*160*4 = 41.9 MB

// ---------------------------------------------------------------------------
// K1: streaming-friendly M layout.
// m1g[l][oct][c][j] = w_r * M[l][c][oct*8+j]   (r = oct*8+j)
// m2g[l][oct][c][j] = w_r * M[c][l][oct*8+j]
// w_0 = 0.5, w_{r>=1} = 0.25; zero for r >= 51 or c >= 151.
// ---------------------------------------------------------------------------
__global__ __launch_bounds__(256) void prep_kernel(const float* __restrict__ M,
                                                   _Float16* __restrict__ m1,
                                                   _Float16* __restrict__ m2,
                                                   float* __restrict__ out) {
    const int l = blockIdx.x;      // 0..150
    const int mat = blockIdx.y;    // 0,1
    if (l == 0 && mat == 0 && threadIdx.x == 0) *out = 0.f;
    _Float16* dst = (mat ? m2 : m1) + (size_t)l * MLB;
    for (int e = threadIdx.x; e < MLB; e += 256) {
        int oct = e / 1280;
        int rem = e - oct * 1280;
        int c = rem >> 3, j = rem & 7;
        int r = oct * 8 + j;
        float v = 0.f;
        if (r < RR && c < CC) {
            size_t src = ((size_t)(mat ? c * CC + l : l * CC + c)) * RR + r;
            v = (r == 0 ? 0.5f : 0.25f) * M[src];
        }
        dst[e] = (_Float16)v;
    }
}

// ---------------------------------------------------------------------------
// K2 (fused transpose+GEMM, 32x32x16 MFMA) — barrier-free DEPTH-3 register
// pipeline, PINNED with sched_barrier(0):
//   - Rounds 2/3 post-mortem: the scheduler collapsed named-stage pipelines
//     to depth-1 (VGPR_Count 68 << 112 needed) by sinking loads next to
//     their uses -> only ~1 KB/wave outstanding -> 2.5 TB/s (Little's law).
//   - Fix: after each step's load cluster, __builtin_amdgcn_sched_barrier(0)
//     forbids the scheduler from moving those loads down past the next
//     compute step. Issue->use distance = 3 steps; waitcnt pass then emits
//     COUNTED vmcnt (it runs after scheduling). One fence per step only —
//     everything else remains free for the scheduler (m141 lesson).
//   - Register math: 3 stages x 28 VGPR + 80 AGPR acc + misc ~= 195 <= 256,
//     occupancy stays 2 waves/SIMD (acc already caps it there).
// Grid 512 = 4 img x 2 rowblk x 64 ks.
// ---------------------------------------------------------------------------
__global__ __launch_bounds__(256, 2) void gemm_kernel(const float* __restrict__ rel,
                                                      const _Float16* __restrict__ m1,
                                                      const _Float16* __restrict__ m2,
                                                      const int* __restrict__ labels,
                                                      float* __restrict__ part) {
    const int tid  = threadIdx.x;
    const int ks   = blockIdx.x & 63;
    const int rbk  = (blockIdx.x >> 6) & 1;
    const int n    = blockIdx.x >> 7;
    const int wave = tid >> 6, lane = tid & 63;
    const int m32  = lane & 31, kh = lane >> 5;
    const int i0   = ks * 4;
    const int rowimg = rbk * 128 + wave * 32 + m32;   // this lane's A row (q, in-image)

    int labs[4];
    #pragma unroll
    for (int j = 0; j < 4; ++j) labs[j] = labels[n * PP + i0 + j];

    floatx16 acc[5];
    #pragma unroll
    for (int ct = 0; ct < 5; ++ct)
        #pragma unroll
        for (int r2 = 0; r2 < 16; ++r2) acc[ct][r2] = 0.f;

    // step h = (i_loc<<3) | (mat<<2) | t ; t = k16-step within the 64 r-slots
    auto loadA = [&](int h, float* v) {
        const int il = h >> 3, mh = (h >> 2) & 1, t = h & 3;
        const int i = i0 + il;
        const int r0 = t * 16 + kh * 8;
        int idx = mh ? ((n * PP + rowimg) * PP + i) * RR + r0
                     : ((n * PP + i) * PP + rowimg) * RR + r0;
        idx = min(idx, ALIM);     // only reachable on the i==q==255 diagonal (zeroed)
        const float* p = rel + idx;
        #pragma unroll
        for (int j = 0; j < 8; ++j) v[j] = p[j];
    };
    auto loadB = [&](int h, half8* b) {
        const int il = h >> 3, mh = (h >> 2) & 1, t = h & 3;
        const _Float16* p = (mh ? m2 : m1) + (size_t)labs[il] * MLB + t * 2560
                          + (size_t)(kh * 160 + m32) * 8;
        #pragma unroll
        for (int ct = 0; ct < 5; ++ct) b[ct] = *(const half8*)(p + ct * 256);
    };
    auto computeStep = [&](int h, const float* av, const half8* bv) {
        const int il = h >> 3;
        const bool dz = (i0 + il) == rowimg;   // diagonal i == q -> zero A row
        half8 a;
        #pragma unroll
        for (int j = 0; j < 8; ++j) a[j] = (_Float16)(dz ? 0.f : av[j]);
        #pragma unroll
        for (int ct = 0; ct < 5; ++ct)
            acc[ct] = __builtin_amdgcn_mfma_f32_32x32x16_f16(a, bv[ct], acc[ct], 0, 0, 0);
    };

    // depth-3 pipeline; stage arrays indexed by (h % 3) which is a
    // compile-time constant after full unroll (rule #20: static indices).
    float aS[3][8];
    half8 bS[3][5];
    loadA(0, aS[0]); loadB(0, bS[0]);
    __builtin_amdgcn_sched_barrier(0);
    loadA(1, aS[1]); loadB(1, bS[1]);
    __builtin_amdgcn_sched_barrier(0);
    loadA(2, aS[2]); loadB(2, bS[2]);
    __builtin_amdgcn_sched_barrier(0);

    #pragma unroll
    for (int h = 0; h < 32; ++h) {
        computeStep(h, aS[h % 3], bS[h % 3]);
        if (h + 3 < 32) {
            loadA(h + 3, aS[(h + 3) % 3]);
            loadB(h + 3, bS[(h + 3) % 3]);
            // Pin: loads for h+3 must be ISSUED before compute(h+1) is
            // scheduled — prevents the depth-collapse seen in rounds 2/3.
            __builtin_amdgcn_sched_barrier(0);
        }
    }

    // C/D 32x32 layout (m74/m101): col = m32, row = (reg&3) + 8*(reg>>2) + 4*kh
    float* pb = part + ((size_t)ks * NROW + n * PP + rbk * 128 + wave * 32) * CM;
    #pragma unroll
    for (int ct = 0; ct < 5; ++ct)
        #pragma unroll
        for (int reg = 0; reg < 16; ++reg) {
            int row = (reg & 3) + 8 * (reg >> 2) + 4 * kh;
            pb[(size_t)row * CM + ct * 32 + m32] = acc[ct][reg];
        }
}

// ---------------------------------------------------------------------------
// K3: theta[row][c] = sum_ks part; loss = lse(theta) - theta[lab]; mean.
// ---------------------------------------------------------------------------
__global__ __launch_bounds__(256) void reduce_loss_kernel(const float* __restrict__ part,
                                                          const int* __restrict__ labels,
                                                          float* __restrict__ out) {
    __shared__ float th[CM];
    const int row = blockIdx.x;
    const int t = threadIdx.x;
    if (t < CM) {
        float s = 0.f;
        #pragma unroll
        for (int ks = 0; ks < KS; ++ks)
            s += part[((size_t)ks * NROW + row) * CM + t];
        th[t] = s;
    }
    __syncthreads();
    if (t < 64) {
        float v0 = (t < CC)       ? th[t]       : -INFINITY;
        float v1 = (t + 64 < CC)  ? th[t + 64]  : -INFINITY;
        float v2 = (t + 128 < CC) ? th[t + 128] : -INFINITY;
        float m = fmaxf(v0, fmaxf(v1, v2));
        #pragma unroll
        for (int o = 32; o > 0; o >>= 1) m = fmaxf(m, __shfl_xor(m, o, 64));
        float s = 0.f;
        if (t < CC)       s += expf(v0 - m);
        if (t + 64 < CC)  s += expf(v1 - m);
        if (t + 128 < CC) s += expf(v2 - m);
        #pragma unroll
        for (int o = 32; o > 0; o >>= 1) s += __shfl_xor(s, o, 64);
        if (t == 0) {
            atomicAdd(out, (m + logf(s) - th[labels[row]]) * (1.0f / NROW));
        }
    }
}

// ---------------------------------------------------------------------------
extern "C" void kernel_launch(void* const* d_in, const int* in_sizes, int n_in,
                              void* d_out, int out_size, void* d_ws, size_t ws_size,
                              hipStream_t stream) {
    // inputs: 0=roi_scores (unused), 1=rel_scores, 2=relationship_mat,
    //         3=roi_labels, 4=num_images (fixed B=4)
    const float* rel    = (const float*)d_in[1];
    const float* relmat = (const float*)d_in[2];
    const int*   labels = (const int*)d_in[3];
    float* out = (float*)d_out;
    char* ws = (char*)d_ws;

    _Float16* m1 = (_Float16*)(ws + OFF_M1);
    _Float16* m2 = (_Float16*)(ws + OFF_M2);
    float*  part = (float*)(ws + OFF_PT);

    prep_kernel<<<dim3(CC, 2), 256, 0, stream>>>(relmat, m1, m2, out);
    gemm_kernel<<<NB * 2 * KS, 256, 0, stream>>>(rel, m1, m2, labels, part);
    reduce_loss_kernel<<<NROW, 256, 0, stream>>>(part, labels, out);
}